// Round 5
// baseline (257.729 us; speedup 1.0000x reference)
//
#include <hip/hip_runtime.h>
#include <hip/hip_cooperative_groups.h>
#include <math.h>

namespace cg = cooperative_groups;

// Problem constants
#define L_SEQ   32768
#define H_DIM   256
#define P_DIM   128
#define P2      256      // 2*P interleaved (re,im)
#define NBLK    256      // fused blocks: 128 rows each = exactly 1 chunk, 1/CU
#define ROWS    128      // rows per block (= chunk length)
#define TPB     1024     // 16 waves per block
#define NW      16       // waves

// workspace layout (float offsets)
#define WS_LB     0                     // Lambda_bar                  256
#define WS_APOW   256                   // [128][P2] Lb^{i+1}          32768
#define WS_A128P  33024                 // [16][P2] Lb^{128d}, d=0..15 4096
#define WS_A2048  37120                 // Lb^2048                     256
#define WS_COEF   37376                 // (Lb-1)/Lambda               256
#define WS_E      37632                 // [256][P2] chunk summaries   65536
#define WS_PACKS  103168                // ushort packs                131072 floats

typedef __attribute__((ext_vector_type(8))) short short8;
typedef __attribute__((ext_vector_type(4))) float f32x4;

#define SAK 264   // LDS k-stride (ushorts) for A tile: 256 + 8 pad
#define STL 260   // LDS float stride for scan tile

// ---------------------------------------------------------------------------
// Full-precision split (RNE both halves) — used for weights.
__device__ __forceinline__ void split_bf16(float v, ushort& hi, ushort& lo) {
    union { float f; unsigned u; } a; a.f = v;
    unsigned r = a.u + 0x7FFFu + ((a.u >> 16) & 1u);   // RNE to bf16
    hi = (ushort)(r >> 16);
    union { unsigned u; float f; } hf; hf.u = ((unsigned)hi) << 16;
    float rem = v - hf.f;
    union { float f; unsigned u; } b; b.f = rem;
    unsigned r2 = b.u + 0x7FFFu + ((b.u >> 16) & 1u);
    lo = (ushort)(r2 >> 16);
}

// Fast split for A-tile staging: trunc hi (lo compensates exactly), RNE lo.
__device__ __forceinline__ void split_bf16_fast(float v, ushort& hi, ushort& lo) {
    union { float f; unsigned u; } a; a.f = v;
    hi = (ushort)(a.u >> 16);                          // trunc toward zero
    union { unsigned u; float f; } hf; hf.u = a.u & 0xFFFF0000u;
    float rem = v - hf.f;                              // exact
    union { float f; unsigned u; } b; b.f = rem;
    unsigned r2 = b.u + 0x7FFFu + ((b.u >> 16) & 1u);  // RNE lo
    lo = (ushort)(r2 >> 16);
}

// two packed complex: returns A*x + f  (layout r0,i0,r1,i1)
__device__ __forceinline__ float4 cfma2(const float4 A, const float4 x, const float4 f) {
    float4 o;
    o.x = A.x * x.x - A.y * x.y + f.x;
    o.y = A.x * x.y + A.y * x.x + f.y;
    o.z = A.z * x.z - A.w * x.w + f.z;
    o.w = A.z * x.w + A.w * x.z + f.w;
    return o;
}

// ---------------------------------------------------------------------------
// Setup 1: per-p quantities. 1 block, 128 threads.
__global__ void k_setup_p(const float* __restrict__ lre, const float* __restrict__ lim,
                          const float* __restrict__ lstep, float* __restrict__ ws) {
    int p = threadIdx.x;
    if (p >= P_DIM) return;
    float step = expf(lstep[p]);
    float lr = lre[p], li = lim[p];
    double zd = (double)lr * (double)step;
    double yd = (double)li * (double)step;
    double ed = exp(zd), cd = cos(yd), sd = sin(yd);
    double lbr = ed * cd, lbi = ed * sd;           // Lambda_bar (double)
    ws[WS_LB + 2*p]     = (float)lbr;
    ws[WS_LB + 2*p + 1] = (float)lbi;
    // Apow[i] = Lb^{i+1}, incremental, i = 0..127
    double mr = lbr, mi = lbi;
    ws[WS_APOW + 2*p]     = (float)mr;
    ws[WS_APOW + 2*p + 1] = (float)mi;
    for (int i = 1; i < 128; i++) {
        double nr = mr * lbr - mi * lbi;
        mi = mr * lbi + mi * lbr;
        mr = nr;
        ws[WS_APOW + i*P2 + 2*p]     = (float)mr;
        ws[WS_APOW + i*P2 + 2*p + 1] = (float)mi;
    }
    // (mr,mi) == Lb^128
    double r128 = mr, i128 = mi;
    // A128P[d] = Lb^{128d}, d = 0..15
    double ar = 1.0, ai = 0.0;
    ws[WS_A128P + 2*p]     = 1.0f;
    ws[WS_A128P + 2*p + 1] = 0.0f;
    for (int d = 1; d < 16; d++) {
        double nr = ar * r128 - ai * i128;
        ai = ar * i128 + ai * r128;
        ar = nr;
        ws[WS_A128P + d*P2 + 2*p]     = (float)ar;
        ws[WS_A128P + d*P2 + 2*p + 1] = (float)ai;
    }
    // A2048 = Lb^2048 = A128P[15] * Lb^128
    double tr = ar * r128 - ai * i128;
    double ti = ar * i128 + ai * r128;
    ws[WS_A2048 + 2*p]     = (float)tr;
    ws[WS_A2048 + 2*p + 1] = (float)ti;
    // coef = (Lb - 1) / Lambda
    float lbrf = (float)lbr, lbif = (float)lbi;
    float a = lbrf - 1.0f, b = lbif;
    float den = lr*lr + li*li;
    ws[WS_COEF + 2*p]     = (a*lr + b*li) / den;
    ws[WS_COEF + 2*p + 1] = (b*lr - a*li) / den;
}

// ---------------------------------------------------------------------------
// Setup 2: build split-bf16 packed weights, layout [n][k] (k contiguous).
__global__ void k_setup_mats(const float* __restrict__ B, const float* __restrict__ C,
                             const float* __restrict__ coef,
                             ushort* __restrict__ w1h, ushort* __restrict__ w1l,
                             ushort* __restrict__ w2h) {
    int t = blockIdx.x * blockDim.x + threadIdx.x;   // 0..16383
    for (int e = t; e < P_DIM * H_DIM; e += 64 * 256) {
        int p = e >> 8;          // 0..127
        int h = e & 255;         // 0..255
        float br = B[(size_t)(p*H_DIM + h)*2 + 0];
        float bi = B[(size_t)(p*H_DIM + h)*2 + 1];
        float cr = coef[2*p], ci = coef[2*p + 1];
        float v1r = cr*br - ci*bi;
        float v1i = cr*bi + ci*br;
        ushort hi, lo;
        split_bf16(v1r, hi, lo);
        w1h[(size_t)(2*p)*256 + h] = hi;  w1l[(size_t)(2*p)*256 + h] = lo;
        split_bf16(v1i, hi, lo);
        w1h[(size_t)(2*p+1)*256 + h] = hi; w1l[(size_t)(2*p+1)*256 + h] = lo;
        float Cr = C[(size_t)(h*P_DIM + p)*2 + 0];
        float Ci = C[(size_t)(h*P_DIM + p)*2 + 1];
        split_bf16(2.0f*Cr, hi, lo);
        w2h[(size_t)h*256 + 2*p] = hi;
        split_bf16(-2.0f*Ci, hi, lo);
        w2h[(size_t)h*256 + 2*p+1] = hi;
    }
}

// ---------------------------------------------------------------------------
// FUSED: GEMM1 (u@W1, split-bf16 MFMA) -> in-LDS chunk scan -> E ->
// grid.sync -> per-block carry (mod-16 wave fold over E with Lb^2048,
// OLDEST-FIRST so earliest chunk gets the highest power) -> apply ->
// restage x from regs -> GEMM2 (@W2) -> out = . + D*u.
// 256 blocks x 1024 thr (16 waves), 1 block/CU, LDS 135168 B.
__global__ __launch_bounds__(TPB, 4) void k_fused(
        const float* __restrict__ u, const ushort* __restrict__ w1h,
        const ushort* __restrict__ w1l, const ushort* __restrict__ w2h,
        float* __restrict__ out, const float* __restrict__ Dv,
        const float* __restrict__ ws, float* __restrict__ E) {
    __shared__ float4 SMraw[8448];               // 135168 B
    ushort* Ah   = (ushort*)SMraw;               // [128][SAK]
    ushort* Al   = Ah + ROWS * SAK;
    float*  Tile = (float*)SMraw;                // [128][STL] alias (133120 B)

    const int t      = threadIdx.x;
    const int lane   = t & 63;
    const int wave   = t >> 6;        // 0..15
    const int lane16 = lane & 15;
    const int quad   = lane >> 4;
    const int blk    = blockIdx.x;
    const int l0     = blk * ROWS;

    // --- phase A: stage u tile (128 x 256) into LDS, split bf16 -----------
    // thread handles rows m = j*16 + wave, float4-col = lane, j = 0..7
    {
        float4 f[8];
        #pragma unroll
        for (int j = 0; j < 8; j++)
            f[j] = *(const float4*)(u + (size_t)(l0 + j*16 + wave) * 256 + lane * 4);
        #pragma unroll
        for (int j = 0; j < 8; j++) {
            const int m = j*16 + wave;
            ushort4 h4, l4;
            split_bf16_fast(f[j].x, h4.x, l4.x);
            split_bf16_fast(f[j].y, h4.y, l4.y);
            split_bf16_fast(f[j].z, h4.z, l4.z);
            split_bf16_fast(f[j].w, h4.w, l4.w);
            *(ushort4*)(&Ah[m * SAK + lane * 4]) = h4;
            *(ushort4*)(&Al[m * SAK + lane * 4]) = l4;
        }
    }
    __syncthreads();

    // --- phase B: K-loop W1 (split B: 3 MFMA), wave owns 16-col slice -----
    f32x4 acc[8];
    #pragma unroll
    for (int i = 0; i < 8; i++) acc[i] = (f32x4){0.f, 0.f, 0.f, 0.f};
    {
        const ushort* WhB = w1h + (size_t)(wave * 16 + lane16) * 256 + quad * 8;
        const ushort* WlB = w1l + (size_t)(wave * 16 + lane16) * 256 + quad * 8;
        #pragma unroll
        for (int kt = 0; kt < 8; kt++) {
            const int k0 = kt * 32;
            short8 ah[8], alo[8];
            #pragma unroll
            for (int mf = 0; mf < 8; mf++) {
                int m = mf * 16 + lane16;
                ah[mf]  = *(const short8*)(&Ah[m * SAK + k0 + quad * 8]);
                alo[mf] = *(const short8*)(&Al[m * SAK + k0 + quad * 8]);
            }
            short8 bh = *(const short8*)(WhB + k0);
            short8 bl = *(const short8*)(WlB + k0);
            #pragma unroll
            for (int mf = 0; mf < 8; mf++) {
                acc[mf] = __builtin_amdgcn_mfma_f32_16x16x32_bf16(ah[mf],  bh, acc[mf], 0, 0, 0);
                acc[mf] = __builtin_amdgcn_mfma_f32_16x16x32_bf16(ah[mf],  bl, acc[mf], 0, 0, 0);
                acc[mf] = __builtin_amdgcn_mfma_f32_16x16x32_bf16(alo[mf], bh, acc[mf], 0, 0, 0);
            }
        }
    }

    // --- phase C: acc -> Tile, hierarchical in-block scan -----------------
    __syncthreads();
    #pragma unroll
    for (int mf = 0; mf < 8; mf++) {
        int row = mf * 16 + quad * 4;
        int col = wave * 16 + lane16;
        #pragma unroll
        for (int r = 0; r < 4; r++)
            Tile[(row + r) * STL + col] = acc[mf][r];
    }
    __syncthreads();
    // wave w scans rows 8w..8w+7, cols 4*lane
    const float4 Alb = *(const float4*)(ws + WS_LB + 4 * lane);
    float4 v[8];
    {
        const float* Trow = Tile + (wave * 8) * STL + 4 * lane;
        float4 x = make_float4(0.f, 0.f, 0.f, 0.f);
        #pragma unroll
        for (int r = 0; r < 8; r++) {
            x = cfma2(Alb, x, *(const float4*)(Trow + r * STL));
            v[r] = x;
        }
    }
    __syncthreads();
    *(float4*)(Tile + wave * STL + 4 * lane) = v[7];   // 16 segment sums
    __syncthreads();
    if (wave == 0) {
        const float4 A8 = *(const float4*)(ws + WS_APOW + 7 * P2 + 4 * lane); // Lb^8
        float4 c = make_float4(0.f, 0.f, 0.f, 0.f);
        #pragma unroll
        for (int j = 0; j < 16; j++) {
            const float4 s = *(const float4*)(Tile + j * STL + 4 * lane);
            *(float4*)(Tile + (16 + j) * STL + 4 * lane) = c;
            c = cfma2(A8, c, s);
        }
    }
    __syncthreads();
    {
        const float4 cs = *(const float4*)(Tile + (16 + wave) * STL + 4 * lane);
        #pragma unroll
        for (int r = 0; r < 8; r++) {
            const float4 ap = *(const float4*)(ws + WS_APOW + (size_t)r * P2 + 4 * lane);
            v[r] = cfma2(ap, cs, v[r]);                // y_local rows wave*8+r
        }
    }
    // chunk summary: y_local[127] (wave 15, r=7)
    if (wave == 15)
        *(float4*)(E + (size_t)blk * P2 + 4 * lane) = v[7];

    __threadfence();
    cg::this_grid().sync();

    // --- phase D: per-block carry from E (mod-16 wave split) --------------
    // c = sum_{j<blk} Lb^{128(blk-1-j)} E[j]; wave w handles j === w (mod 16).
    // Fold OLDEST-FIRST (j ascending): p = A2048*p + E[j] gives E[w] the
    // highest power, E[jmax] weight 1; then align by Lb^{128(blk-1-jmax)}.
    float4 c = make_float4(0.f, 0.f, 0.f, 0.f);
    {
        float4 p = make_float4(0.f, 0.f, 0.f, 0.f);
        const int cnt = (blk > wave) ? (((blk - 1 - wave) >> 4) + 1) : 0;
        if (cnt > 0) {
            const float4 A2 = *(const float4*)(ws + WS_A2048 + 4 * lane);
            const float* ep = E + (size_t)wave * P2 + 4 * lane;
            #pragma unroll 4
            for (int m = 0; m < cnt; m++) {
                p = cfma2(A2, p, *(const float4*)ep);
                ep += 16 * P2;
            }
            const int jmax = wave + ((cnt - 1) << 4);
            const int d = blk - 1 - jmax;              // 0..15
            const float4 Ad = *(const float4*)(ws + WS_A128P + (size_t)d * P2 + 4 * lane);
            const float4 z = make_float4(0.f, 0.f, 0.f, 0.f);
            p = cfma2(Ad, p, z);
        }
        *(float4*)(Tile + wave * STL + 4 * lane) = p;
        __syncthreads();
        #pragma unroll
        for (int w2 = 0; w2 < NW; w2++) {
            const float4 q = *(const float4*)(Tile + w2 * STL + 4 * lane);
            c.x += q.x; c.y += q.y; c.z += q.z; c.w += q.w;
        }
    }

    // --- phase E: apply carry, restage x (regs -> Ah/Al) ------------------
    #pragma unroll
    for (int r = 0; r < 8; r++) {
        const float4 ap = *(const float4*)(ws + WS_APOW + (size_t)(wave * 8 + r) * P2 + 4 * lane);
        v[r] = cfma2(ap, c, v[r]);                     // x rows wave*8+r
    }
    __syncthreads();   // Tile reads done before Ah/Al overwrite (alias)
    #pragma unroll
    for (int r = 0; r < 8; r++) {
        const int m = wave * 8 + r;
        ushort4 h4, l4;
        split_bf16_fast(v[r].x, h4.x, l4.x);
        split_bf16_fast(v[r].y, h4.y, l4.y);
        split_bf16_fast(v[r].z, h4.z, l4.z);
        split_bf16_fast(v[r].w, h4.w, l4.w);
        *(ushort4*)(&Ah[m * SAK + lane * 4]) = h4;
        *(ushort4*)(&Al[m * SAK + lane * 4]) = l4;
    }
    __syncthreads();

    // --- phase F: K-loop W2 (hi-only B: 2 MFMA) ---------------------------
    f32x4 acc2[8];
    #pragma unroll
    for (int i = 0; i < 8; i++) acc2[i] = (f32x4){0.f, 0.f, 0.f, 0.f};
    {
        const ushort* W2B = w2h + (size_t)(wave * 16 + lane16) * 256 + quad * 8;
        #pragma unroll
        for (int kt = 0; kt < 8; kt++) {
            const int k0 = kt * 32;
            short8 ah[8], alo[8];
            #pragma unroll
            for (int mf = 0; mf < 8; mf++) {
                int m = mf * 16 + lane16;
                ah[mf]  = *(const short8*)(&Ah[m * SAK + k0 + quad * 8]);
                alo[mf] = *(const short8*)(&Al[m * SAK + k0 + quad * 8]);
            }
            short8 bh = *(const short8*)(W2B + k0);
            #pragma unroll
            for (int mf = 0; mf < 8; mf++) {
                acc2[mf] = __builtin_amdgcn_mfma_f32_16x16x32_bf16(ah[mf],  bh, acc2[mf], 0, 0, 0);
                acc2[mf] = __builtin_amdgcn_mfma_f32_16x16x32_bf16(alo[mf], bh, acc2[mf], 0, 0, 0);
            }
        }
    }

    // --- phase G: acc2 -> Tile, epilogue out = . + D*u --------------------
    __syncthreads();
    #pragma unroll
    for (int mf = 0; mf < 8; mf++) {
        int row = mf * 16 + quad * 4;
        int col = wave * 16 + lane16;
        #pragma unroll
        for (int r = 0; r < 4; r++)
            Tile[(row + r) * STL + col] = acc2[mf][r];
    }
    __syncthreads();
    {
        const float4 dv = *(const float4*)(Dv + 4 * lane);
        #pragma unroll
        for (int r = 0; r < 8; r++) {
            const int row = wave * 8 + r;
            const float4 tv = *(const float4*)(Tile + row * STL + 4 * lane);
            const float4 uv = *(const float4*)(u + (size_t)(l0 + row) * 256 + 4 * lane);
            float4 y;
            y.x = tv.x + dv.x * uv.x;
            y.y = tv.y + dv.y * uv.y;
            y.z = tv.z + dv.z * uv.z;
            y.w = tv.w + dv.w * uv.w;
            *(float4*)(out + (size_t)(l0 + row) * 256 + 4 * lane) = y;
        }
    }
}

// ---------------------------------------------------------------------------
extern "C" void kernel_launch(void* const* d_in, const int* in_sizes, int n_in,
                              void* d_out, int out_size, void* d_ws, size_t ws_size,
                              hipStream_t stream) {
    const float* lre   = (const float*)d_in[0];  // Lambda_re (P)
    const float* lim   = (const float*)d_in[1];  // Lambda_im (P)
    const float* B     = (const float*)d_in[2];  // (P,H,2)
    const float* C     = (const float*)d_in[3];  // (H,P,2)
    const float* D     = (const float*)d_in[4];  // (H)
    const float* lstep = (const float*)d_in[5];  // (P)
    const float* u     = (const float*)d_in[6];  // (L,H)
    float* out = (float*)d_out;                  // (L,H)
    float* ws  = (float*)d_ws;
    ushort* wpk = (ushort*)(ws + WS_PACKS);
    ushort* w1h = wpk;
    ushort* w1l = wpk + 65536;
    ushort* w2h = wpk + 131072;
    float* E = ws + WS_E;

    k_setup_p<<<1, 128, 0, stream>>>(lre, lim, lstep, ws);
    k_setup_mats<<<64, 256, 0, stream>>>(B, C, ws + WS_COEF, w1h, w1l, w2h);

    void* args[] = { (void*)&u, (void*)&w1h, (void*)&w1l, (void*)&w2h,
                     (void*)&out, (void*)&D, (void*)&ws, (void*)&E };
    hipLaunchCooperativeKernel((void*)k_fused, dim3(NBLK), dim3(TPB),
                               args, 0, stream);
}

// Round 6
// 151.843 us; speedup vs baseline: 1.6973x; 1.6973x over previous
//
#include <hip/hip_runtime.h>
#include <math.h>

// Problem constants
#define L_SEQ   32768
#define H_DIM   256
#define P_DIM   128
#define P2      256      // 2*P interleaved (re,im)
#define NBLK    256      // GEMM blocks: 128 rows each = exactly 1 chunk
#define ROWS    128      // rows per block (= chunk length)
#define TPB     1024     // 16 waves per block
#define NW      16       // waves
#define NSEG    64       // carry segments
#define CPS     4        // chunks per segment (64*4 = 256 chunks)

// workspace layout (float offsets)
#define WS_LB    0                      // Lambda_bar                  256
#define WS_A128  256                    // Lambda_bar^128              256
#define WS_A512  512                    // Lambda_bar^512              256
#define WS_COEF  768                    // (Lb-1)/Lambda               256
#define WS_APOW  1024                   // [128][P2] Lb^{i+1}          32768
#define WS_E     33792                  // [256][P2] chunk summaries   65536
#define WS_CB    99328                  // [256][P2] carry             65536
#define WS_PACKS 164864                 // ushort packs                131072 floats
#define WS_XS    295936                 // [L][P2] xs                  8388608
#define WS_S     8684544                // [64][P2] segment sums       16384
#define WS_SC    8700928                // [64][P2] segment carry      16384

typedef __attribute__((ext_vector_type(8))) short short8;
typedef __attribute__((ext_vector_type(4))) float f32x4;

#define SAK 264   // LDS k-stride (ushorts) for A tile: 256 + 8 pad (2-way only)
#define STL 260   // LDS float stride for scan tile

// ---------------------------------------------------------------------------
// Full-precision split (RNE both halves) — used for weights.
__device__ __forceinline__ void split_bf16(float v, ushort& hi, ushort& lo) {
    union { float f; unsigned u; } a; a.f = v;
    unsigned r = a.u + 0x7FFFu + ((a.u >> 16) & 1u);   // RNE to bf16
    hi = (ushort)(r >> 16);
    union { unsigned u; float f; } hf; hf.u = ((unsigned)hi) << 16;
    float rem = v - hf.f;
    union { float f; unsigned u; } b; b.f = rem;
    unsigned r2 = b.u + 0x7FFFu + ((b.u >> 16) & 1u);
    lo = (ushort)(r2 >> 16);
}

// Fast split for A-tile staging: trunc hi (lo compensates exactly), RNE lo.
__device__ __forceinline__ void split_bf16_fast(float v, ushort& hi, ushort& lo) {
    union { float f; unsigned u; } a; a.f = v;
    hi = (ushort)(a.u >> 16);                          // trunc toward zero
    union { unsigned u; float f; } hf; hf.u = a.u & 0xFFFF0000u;
    float rem = v - hf.f;                              // exact
    union { float f; unsigned u; } b; b.f = rem;
    unsigned r2 = b.u + 0x7FFFu + ((b.u >> 16) & 1u);  // RNE lo
    lo = (ushort)(r2 >> 16);
}

// two packed complex: returns A*x + f  (layout r0,i0,r1,i1)
__device__ __forceinline__ float4 cfma2(const float4 A, const float4 x, const float4 f) {
    float4 o;
    o.x = A.x * x.x - A.y * x.y + f.x;
    o.y = A.x * x.y + A.y * x.x + f.y;
    o.z = A.z * x.z - A.w * x.w + f.z;
    o.w = A.z * x.w + A.w * x.z + f.w;
    return o;
}

// ---------------------------------------------------------------------------
// Setup 1: per-p quantities. 1 block, 128 threads.
__global__ void k_setup_p(const float* __restrict__ lre, const float* __restrict__ lim,
                          const float* __restrict__ lstep, float* __restrict__ ws) {
    int p = threadIdx.x;
    if (p >= P_DIM) return;
    float step = expf(lstep[p]);
    float lr = lre[p], li = lim[p];
    double zd = (double)lr * (double)step;
    double yd = (double)li * (double)step;
    double ed = exp(zd), cd = cos(yd), sd = sin(yd);
    double lbr = ed * cd, lbi = ed * sd;           // Lambda_bar (double)
    ws[WS_LB + 2*p]     = (float)lbr;
    ws[WS_LB + 2*p + 1] = (float)lbi;
    // Apow[i] = Lb^{i+1}, incremental, i = 0..127  (Apow[127] = Lb^128)
    double mr = lbr, mi = lbi;
    ws[WS_APOW + 2*p]     = (float)mr;
    ws[WS_APOW + 2*p + 1] = (float)mi;
    for (int i = 1; i < 128; i++) {
        double nr = mr * lbr - mi * lbi;
        mi = mr * lbi + mi * lbr;
        mr = nr;
        ws[WS_APOW + i*P2 + 2*p]     = (float)mr;
        ws[WS_APOW + i*P2 + 2*p + 1] = (float)mi;
    }
    // (mr,mi) == Lb^128
    ws[WS_A128 + 2*p]     = (float)mr;
    ws[WS_A128 + 2*p + 1] = (float)mi;
    // A512 = (Lb^128)^4 via 2 squarings
    double ar = mr, ai = mi;
    for (int j = 0; j < 2; j++) {
        double nr = ar*ar - ai*ai;
        ai = 2.0 * ar * ai;
        ar = nr;
    }
    ws[WS_A512 + 2*p]     = (float)ar;
    ws[WS_A512 + 2*p + 1] = (float)ai;
    // coef = (Lb - 1) / Lambda
    float lbrf = (float)lbr, lbif = (float)lbi;
    float a = lbrf - 1.0f, b = lbif;
    float den = lr*lr + li*li;
    ws[WS_COEF + 2*p]     = (a*lr + b*li) / den;
    ws[WS_COEF + 2*p + 1] = (b*lr - a*li) / den;
}

// ---------------------------------------------------------------------------
// Setup 2: build split-bf16 packed weights, layout [n][k] (k contiguous).
__global__ void k_setup_mats(const float* __restrict__ B, const float* __restrict__ C,
                             const float* __restrict__ coef,
                             ushort* __restrict__ w1h, ushort* __restrict__ w1l,
                             ushort* __restrict__ w2h) {
    int t = blockIdx.x * blockDim.x + threadIdx.x;   // 0..16383
    for (int e = t; e < P_DIM * H_DIM; e += 64 * 256) {
        int p = e >> 8;          // 0..127
        int h = e & 255;         // 0..255
        float br = B[(size_t)(p*H_DIM + h)*2 + 0];
        float bi = B[(size_t)(p*H_DIM + h)*2 + 1];
        float cr = coef[2*p], ci = coef[2*p + 1];
        float v1r = cr*br - ci*bi;
        float v1i = cr*bi + ci*br;
        ushort hi, lo;
        split_bf16(v1r, hi, lo);
        w1h[(size_t)(2*p)*256 + h] = hi;  w1l[(size_t)(2*p)*256 + h] = lo;
        split_bf16(v1i, hi, lo);
        w1h[(size_t)(2*p+1)*256 + h] = hi; w1l[(size_t)(2*p+1)*256 + h] = lo;
        float Cr = C[(size_t)(h*P_DIM + p)*2 + 0];
        float Ci = C[(size_t)(h*P_DIM + p)*2 + 1];
        split_bf16(2.0f*Cr, hi, lo);
        w2h[(size_t)h*256 + 2*p] = hi;
        split_bf16(-2.0f*Ci, hi, lo);
        w2h[(size_t)h*256 + 2*p+1] = hi;
    }
}

// ---------------------------------------------------------------------------
// Carry, two-level parallel. Chunk advance Lb^128, segment advance Lb^512.
__global__ void k_carry_reduce(const float* __restrict__ E, float* __restrict__ S,
                               const float* __restrict__ a128) {
    const int s = blockIdx.x;          // segment 0..63
    const int q = threadIdx.x;         // 0..63
    const float4 A = *(const float4*)(a128 + 4 * q);
    const float* xe = E + (size_t)s * CPS * P2 + 4 * q;
    float4 e = make_float4(0.f, 0.f, 0.f, 0.f);
    #pragma unroll
    for (int j = 0; j < CPS; j++)
        e = cfma2(A, e, *(const float4*)(xe + (size_t)j * P2));
    *(float4*)(S + (size_t)s * P2 + 4 * q) = e;
}

__global__ void k_carry_scan(const float* __restrict__ S, float* __restrict__ SC,
                             const float* __restrict__ a512) {
    const int q = threadIdx.x;         // 0..63
    const float4 AS = *(const float4*)(a512 + 4 * q);
    float4 c = make_float4(0.f, 0.f, 0.f, 0.f);
    #pragma unroll 8
    for (int s = 0; s < NSEG; s++) {
        *(float4*)(SC + (size_t)s * P2 + 4 * q) = c;
        c = cfma2(AS, c, *(const float4*)(S + (size_t)s * P2 + 4 * q));
    }
}

__global__ void k_carry_apply(const float* __restrict__ E, const float* __restrict__ SC,
                              float* __restrict__ cb, const float* __restrict__ a128) {
    const int s = blockIdx.x;
    const int q = threadIdx.x;
    const float4 A = *(const float4*)(a128 + 4 * q);
    const float* xe = E + (size_t)s * CPS * P2 + 4 * q;
    float* cw = cb + (size_t)s * CPS * P2 + 4 * q;
    float4 c = *(const float4*)(SC + (size_t)s * P2 + 4 * q);
    #pragma unroll
    for (int j = 0; j < CPS; j++) {
        *(float4*)(cw + (size_t)j * P2) = c;
        c = cfma2(A, c, *(const float4*)(xe + (size_t)j * P2));
    }
}

// ---------------------------------------------------------------------------
// MFMA split-bf16 GEMM: C[l][n] = sum_k A[l][k] * W[k][n]
// M=32768 (256 blocks x 128 rows = 1 chunk), N=256 full, K=256.
// 1024 threads = 16 waves; wave w owns 16-col slice; 8 mf x 1 nf frags.
// ROWS=128 halves the weight L2 stream vs ROWS=64 (the proven R3 lever).
// Lean K-loop live set (bh/bl once per kt, per-mf {ds_read, 3 MFMA}) to
// avoid the R5 spill failure. LDS 135168 B -> 1 block/CU, 16 waves/CU.
template<bool EPI, bool APPLY, bool SCAN, bool BSPLIT>
__global__ __launch_bounds__(TPB, 4) void k_gemm_mfma(
        const float* __restrict__ A, const ushort* __restrict__ Wh,
        const ushort* __restrict__ Wl, float* __restrict__ Cmat,
        const float* __restrict__ Dv, const float* __restrict__ U,
        const float* __restrict__ ws, float* __restrict__ Eout,
        const float* __restrict__ cbin) {
    __shared__ float4 SMraw[8448];               // 135168 B
    ushort* Ah   = (ushort*)SMraw;               // [128][SAK]
    ushort* Al   = Ah + ROWS * SAK;
    float*  Tile = (float*)SMraw;                // [128][STL] alias (133120 B)

    const int t      = threadIdx.x;
    const int lane   = t & 63;
    const int wave   = t >> 6;        // 0..15
    const int lane16 = lane & 15;
    const int quad   = lane >> 4;
    const int blk    = blockIdx.x;
    const int l0     = blk * ROWS;

    // --- stage full A tile (128 x 256) into LDS, split bf16 ---------------
    // thread handles rows m = j*16 + wave, float4-col = lane, j = 0..7
    {
        float4 f[8];
        #pragma unroll
        for (int j = 0; j < 8; j++)
            f[j] = *(const float4*)(A + (size_t)(l0 + j*16 + wave) * 256 + lane * 4);
        if (APPLY) {
            const float4 cr = *(const float4*)(cbin + (size_t)blk * P2 + lane * 4);
            #pragma unroll
            for (int j = 0; j < 8; j++) {
                const float4 ap = *(const float4*)(ws + WS_APOW + (size_t)(j*16 + wave) * P2 + lane * 4);
                f[j] = cfma2(ap, cr, f[j]);
            }
        }
        #pragma unroll
        for (int j = 0; j < 8; j++) {
            const int m = j*16 + wave;
            ushort4 h4, l4;
            split_bf16_fast(f[j].x, h4.x, l4.x);
            split_bf16_fast(f[j].y, h4.y, l4.y);
            split_bf16_fast(f[j].z, h4.z, l4.z);
            split_bf16_fast(f[j].w, h4.w, l4.w);
            *(ushort4*)(&Ah[m * SAK + lane * 4]) = h4;
            *(ushort4*)(&Al[m * SAK + lane * 4]) = l4;
        }
    }
    __syncthreads();

    f32x4 acc[8];
    #pragma unroll
    for (int i = 0; i < 8; i++) acc[i] = (f32x4){0.f, 0.f, 0.f, 0.f};

    // b-frag base: wave's 16-col slice; quads form one contiguous 64 B segment
    const ushort* WhB = Wh + (size_t)(wave * 16 + lane16) * 256 + quad * 8;
    const ushort* WlB = Wl + (size_t)(wave * 16 + lane16) * 256 + quad * 8;

    // --- K-loop: barrier-free, lean live set ------------------------------
    #pragma unroll
    for (int kt = 0; kt < 8; kt++) {
        const int k0 = kt * 32;
        short8 bh = *(const short8*)(WhB + k0);
        short8 bl;
        if (BSPLIT) bl = *(const short8*)(WlB + k0);
        #pragma unroll
        for (int mf = 0; mf < 8; mf++) {
            const int m = mf * 16 + lane16;
            short8 ah  = *(const short8*)(&Ah[m * SAK + k0 + quad * 8]);
            short8 alo = *(const short8*)(&Al[m * SAK + k0 + quad * 8]);
            acc[mf] = __builtin_amdgcn_mfma_f32_16x16x32_bf16(ah,  bh, acc[mf], 0, 0, 0);
            if (BSPLIT)
                acc[mf] = __builtin_amdgcn_mfma_f32_16x16x32_bf16(ah, bl, acc[mf], 0, 0, 0);
            acc[mf] = __builtin_amdgcn_mfma_f32_16x16x32_bf16(alo, bh, acc[mf], 0, 0, 0);
        }
    }

    // --- dump acc into LDS tile (staging dead) ----------------------------
    __syncthreads();
    #pragma unroll
    for (int mf = 0; mf < 8; mf++) {
        int row = mf * 16 + quad * 4;
        int col = wave * 16 + lane16;
        #pragma unroll
        for (int r = 0; r < 4; r++)
            Tile[(row + r) * STL + col] = acc[mf][r];
    }
    __syncthreads();

    if (!SCAN) {
        // epilogue via Tile: vectorized out = Tile + D .* U, float4 I/O
        const float4 dv = *(const float4*)(Dv + 4 * lane);
        #pragma unroll
        for (int r = 0; r < 8; r++) {
            const int row = wave * 8 + r;
            const float4 tv = *(const float4*)(Tile + row * STL + 4 * lane);
            float4 y = tv;
            if (EPI) {
                const float4 uv = *(const float4*)(U + (size_t)(l0 + row) * 256 + 4 * lane);
                y.x += dv.x * uv.x;  y.y += dv.y * uv.y;
                y.z += dv.z * uv.z;  y.w += dv.w * uv.w;
            }
            *(float4*)(Cmat + (size_t)(l0 + row) * 256 + 4 * lane) = y;
        }
    } else {
        // hierarchical parallel scan: wave w owns rows 8w..8w+7 (R5-verified)
        const float4 Alb = *(const float4*)(ws + WS_LB + 4 * lane);
        float4 v[8];
        {
            const float* Trow = Tile + (wave * 8) * STL + 4 * lane;
            float4 x = make_float4(0.f, 0.f, 0.f, 0.f);
            #pragma unroll
            for (int r = 0; r < 8; r++) {
                x = cfma2(Alb, x, *(const float4*)(Trow + r * STL));
                v[r] = x;
            }
        }
        __syncthreads();
        *(float4*)(Tile + wave * STL + 4 * lane) = v[7];   // 16 segment sums
        __syncthreads();
        if (wave == 0) {
            const float4 A8 = *(const float4*)(ws + WS_APOW + 7 * P2 + 4 * lane); // Lb^8
            float4 c = make_float4(0.f, 0.f, 0.f, 0.f);
            #pragma unroll
            for (int j = 0; j < 16; j++) {
                const float4 s = *(const float4*)(Tile + j * STL + 4 * lane);
                *(float4*)(Tile + (16 + j) * STL + 4 * lane) = c;
                c = cfma2(A8, c, s);
            }
        }
        __syncthreads();
        const float4 cs = *(const float4*)(Tile + (16 + wave) * STL + 4 * lane);
        // xs_local[8w+r] = v_r + Lb^{r+1} * cs ; store immediately
        float* gbase = Cmat + (size_t)(l0 + wave * 8) * 256 + 4 * lane;
        #pragma unroll
        for (int r = 0; r < 8; r++) {
            const float4 ap = *(const float4*)(ws + WS_APOW + (size_t)r * P2 + 4 * lane);
            const float4 y = cfma2(ap, cs, v[r]);
            *(float4*)(gbase + (size_t)r * 256) = y;
            if (r == 7 && wave == 15)
                *(float4*)(Eout + (size_t)blk * P2 + 4 * lane) = y;  // chunk sum
        }
    }
}

// ---------------------------------------------------------------------------
extern "C" void kernel_launch(void* const* d_in, const int* in_sizes, int n_in,
                              void* d_out, int out_size, void* d_ws, size_t ws_size,
                              hipStream_t stream) {
    const float* lre   = (const float*)d_in[0];  // Lambda_re (P)
    const float* lim   = (const float*)d_in[1];  // Lambda_im (P)
    const float* B     = (const float*)d_in[2];  // (P,H,2)
    const float* C     = (const float*)d_in[3];  // (H,P,2)
    const float* D     = (const float*)d_in[4];  // (H)
    const float* lstep = (const float*)d_in[5];  // (P)
    const float* u     = (const float*)d_in[6];  // (L,H)
    float* out = (float*)d_out;                  // (L,H) final output only
    float* ws  = (float*)d_ws;
    float* xs  = ws + WS_XS;                     // (L,P2) scan state
    ushort* wpk = (ushort*)(ws + WS_PACKS);
    ushort* w1h = wpk;
    ushort* w1l = wpk + 65536;
    ushort* w2h = wpk + 131072;

    k_setup_p<<<1, 128, 0, stream>>>(lre, lim, lstep, ws);
    k_setup_mats<<<64, 256, 0, stream>>>(B, C, ws + WS_COEF, w1h, w1l, w2h);
    // GEMM1: xs_local = scan_local(u @ W1) -> ws, chunk summaries E
    k_gemm_mfma<false, false, true, true><<<NBLK, TPB, 0, stream>>>(
        u, w1h, w1l, xs, nullptr, nullptr, ws, ws + WS_E, nullptr);
    // carry across 256 chunks: two-level parallel scan (64-way)
    k_carry_reduce<<<NSEG, 64, 0, stream>>>(ws + WS_E, ws + WS_S, ws + WS_A128);
    k_carry_scan<<<1, 64, 0, stream>>>(ws + WS_S, ws + WS_SC, ws + WS_A512);
    k_carry_apply<<<NSEG, 64, 0, stream>>>(ws + WS_E, ws + WS_SC, ws + WS_CB,
                                           ws + WS_A128);
    // GEMM2: out = (xs_local + Apow*carry) @ W2 + D*u
    k_gemm_mfma<true, true, false, false><<<NBLK, TPB, 0, stream>>>(
        xs, w2h, nullptr, out, D, u, ws, nullptr, ws + WS_CB);
}

// Round 7
// 147.554 us; speedup vs baseline: 1.7467x; 1.0291x over previous
//
#include <hip/hip_runtime.h>
#include <math.h>

// Problem constants
#define L_SEQ   32768
#define H_DIM   256
#define P_DIM   128
#define P2      256      // 2*P interleaved (re,im)
#define NBLK    512      // blocks: 64 rows each = exactly 1 chunk
#define ROWS    64       // rows per block (= chunk length)
#define TPB     512      // 8 waves per block
#define NW      8        // waves

// workspace layout (float offsets)
#define WS_LB    0                      // Lambda_bar                  256
#define WS_A64P  256                    // [8][P2] Lb^{64d}, d=0..7    2048
#define WS_A512  2304                   // Lb^512                      256
#define WS_COEF  2560                   // (Lb-1)/Lambda               256
#define WS_APOW  2816                   // [64][P2] Lb^{i+1}           16384
#define WS_E     19200                  // [512][P2] chunk summaries   131072
#define WS_PACKS 150272                 // ushort packs (3x32768 f)    98304
#define WS_XS16  248576                 // [L][P2] xs bf16 (ushort)    4194304 f

typedef __attribute__((ext_vector_type(8))) short short8;
typedef __attribute__((ext_vector_type(4))) float f32x4;

#define SAK 264   // LDS k-stride (ushorts) for A tile: 256 + 8 pad (2-way only)
#define STL 260   // LDS float stride for scan tile

// ---------------------------------------------------------------------------
// Full-precision split (RNE both halves) — used for weights.
__device__ __forceinline__ void split_bf16(float v, ushort& hi, ushort& lo) {
    union { float f; unsigned u; } a; a.f = v;
    unsigned r = a.u + 0x7FFFu + ((a.u >> 16) & 1u);   // RNE to bf16
    hi = (ushort)(r >> 16);
    union { unsigned u; float f; } hf; hf.u = ((unsigned)hi) << 16;
    float rem = v - hf.f;
    union { float f; unsigned u; } b; b.f = rem;
    unsigned r2 = b.u + 0x7FFFu + ((b.u >> 16) & 1u);
    lo = (ushort)(r2 >> 16);
}

// Fast split for A-tile staging: trunc hi (lo compensates exactly), RNE lo.
__device__ __forceinline__ void split_bf16_fast(float v, ushort& hi, ushort& lo) {
    union { float f; unsigned u; } a; a.f = v;
    hi = (ushort)(a.u >> 16);                          // trunc toward zero
    union { unsigned u; float f; } hf; hf.u = a.u & 0xFFFF0000u;
    float rem = v - hf.f;                              // exact
    union { float f; unsigned u; } b; b.f = rem;
    unsigned r2 = b.u + 0x7FFFu + ((b.u >> 16) & 1u);  // RNE lo
    lo = (ushort)(r2 >> 16);
}

__device__ __forceinline__ ushort rne_bf16(float v) {
    union { float f; unsigned u; } a; a.f = v;
    return (ushort)((a.u + 0x7FFFu + ((a.u >> 16) & 1u)) >> 16);
}

__device__ __forceinline__ float bf16_to_f32(ushort h) {
    union { unsigned u; float f; } b; b.u = ((unsigned)h) << 16;
    return b.f;
}

// two packed complex: returns A*x + f  (layout r0,i0,r1,i1)
__device__ __forceinline__ float4 cfma2(const float4 A, const float4 x, const float4 f) {
    float4 o;
    o.x = A.x * x.x - A.y * x.y + f.x;
    o.y = A.x * x.y + A.y * x.x + f.y;
    o.z = A.z * x.z - A.w * x.w + f.z;
    o.w = A.z * x.w + A.w * x.z + f.w;
    return o;
}

// ---------------------------------------------------------------------------
// Setup 1: per-p quantities. 1 block, 128 threads.
__global__ void k_setup_p(const float* __restrict__ lre, const float* __restrict__ lim,
                          const float* __restrict__ lstep, float* __restrict__ ws) {
    int p = threadIdx.x;
    if (p >= P_DIM) return;
    float step = expf(lstep[p]);
    float lr = lre[p], li = lim[p];
    double zd = (double)lr * (double)step;
    double yd = (double)li * (double)step;
    double ed = exp(zd), cd = cos(yd), sd = sin(yd);
    double lbr = ed * cd, lbi = ed * sd;           // Lambda_bar (double)
    ws[WS_LB + 2*p]     = (float)lbr;
    ws[WS_LB + 2*p + 1] = (float)lbi;
    // Apow[i] = Lb^{i+1}, incremental, i = 0..63  (Apow[63] = Lb^64)
    double mr = lbr, mi = lbi;
    ws[WS_APOW + 2*p]     = (float)mr;
    ws[WS_APOW + 2*p + 1] = (float)mi;
    for (int i = 1; i < 64; i++) {
        double nr = mr * lbr - mi * lbi;
        mi = mr * lbi + mi * lbr;
        mr = nr;
        ws[WS_APOW + i*P2 + 2*p]     = (float)mr;
        ws[WS_APOW + i*P2 + 2*p + 1] = (float)mi;
    }
    // (mr,mi) == Lb^64.  A64P[d] = Lb^{64d}, d = 0..7
    double ar = 1.0, ai = 0.0;
    ws[WS_A64P + 2*p]     = 1.0f;
    ws[WS_A64P + 2*p + 1] = 0.0f;
    for (int d = 1; d < 8; d++) {
        double nr = ar * mr - ai * mi;
        ai = ar * mi + ai * mr;
        ar = nr;
        ws[WS_A64P + d*P2 + 2*p]     = (float)ar;
        ws[WS_A64P + d*P2 + 2*p + 1] = (float)ai;
    }
    // A512 = Lb^512 = A64P[7] * Lb^64
    double tr = ar * mr - ai * mi;
    double ti = ar * mi + ai * mr;
    ws[WS_A512 + 2*p]     = (float)tr;
    ws[WS_A512 + 2*p + 1] = (float)ti;
    // coef = (Lb - 1) / Lambda
    float lbrf = (float)lbr, lbif = (float)lbi;
    float a = lbrf - 1.0f, b = lbif;
    float den = lr*lr + li*li;
    ws[WS_COEF + 2*p]     = (a*lr + b*li) / den;
    ws[WS_COEF + 2*p + 1] = (b*lr - a*li) / den;
}

// ---------------------------------------------------------------------------
// Setup 2: build split-bf16 packed weights, layout [n][k] (k contiguous).
__global__ void k_setup_mats(const float* __restrict__ B, const float* __restrict__ C,
                             const float* __restrict__ coef,
                             ushort* __restrict__ w1h, ushort* __restrict__ w1l,
                             ushort* __restrict__ w2h) {
    int t = blockIdx.x * blockDim.x + threadIdx.x;   // 0..16383
    for (int e = t; e < P_DIM * H_DIM; e += 64 * 256) {
        int p = e >> 8;          // 0..127
        int h = e & 255;         // 0..255
        float br = B[(size_t)(p*H_DIM + h)*2 + 0];
        float bi = B[(size_t)(p*H_DIM + h)*2 + 1];
        float cr = coef[2*p], ci = coef[2*p + 1];
        float v1r = cr*br - ci*bi;
        float v1i = cr*bi + ci*br;
        ushort hi, lo;
        split_bf16(v1r, hi, lo);
        w1h[(size_t)(2*p)*256 + h] = hi;  w1l[(size_t)(2*p)*256 + h] = lo;
        split_bf16(v1i, hi, lo);
        w1h[(size_t)(2*p+1)*256 + h] = hi; w1l[(size_t)(2*p+1)*256 + h] = lo;
        float Cr = C[(size_t)(h*P_DIM + p)*2 + 0];
        float Ci = C[(size_t)(h*P_DIM + p)*2 + 1];
        split_bf16(2.0f*Cr, hi, lo);
        w2h[(size_t)h*256 + 2*p] = hi;
        split_bf16(-2.0f*Ci, hi, lo);
        w2h[(size_t)h*256 + 2*p+1] = hi;
    }
}

// ---------------------------------------------------------------------------
// GEMM1 (R3-proven config): xs_local = scan_local(u @ W1), split-bf16 MFMA.
// 512 blocks x 512 thr (8 waves); wave owns 32-col slice; 4 mf x 2 nf.
// Scan epilogue writes xs as bf16 (halves the HBM round-trip) + E (f32).
__global__ __launch_bounds__(TPB, 4) void k_gemm1(
        const float* __restrict__ u, const ushort* __restrict__ Wh,
        const ushort* __restrict__ Wl, ushort* __restrict__ xs16,
        const float* __restrict__ ws, float* __restrict__ E) {
    __shared__ float4 SMraw[4224];               // 67584 B
    ushort* Ah   = (ushort*)SMraw;               // [64][SAK]
    ushort* Al   = Ah + ROWS * SAK;
    float*  Tile = (float*)SMraw;                // [64][STL] alias (66560 B)

    const int t      = threadIdx.x;
    const int lane   = t & 63;
    const int wave   = t >> 6;        // 0..7
    const int lane16 = lane & 15;
    const int quad   = lane >> 4;
    const int blk    = blockIdx.x;
    const int l0     = blk * ROWS;

    // --- stage u tile (64 x 256) into LDS, split bf16 ---------------------
    {
        float4 f[8];
        #pragma unroll
        for (int j = 0; j < 8; j++)
            f[j] = *(const float4*)(u + (size_t)(l0 + j*8 + wave) * 256 + lane * 4);
        #pragma unroll
        for (int j = 0; j < 8; j++) {
            const int m = j*8 + wave;
            ushort4 h4, l4;
            split_bf16_fast(f[j].x, h4.x, l4.x);
            split_bf16_fast(f[j].y, h4.y, l4.y);
            split_bf16_fast(f[j].z, h4.z, l4.z);
            split_bf16_fast(f[j].w, h4.w, l4.w);
            *(ushort4*)(&Ah[m * SAK + lane * 4]) = h4;
            *(ushort4*)(&Al[m * SAK + lane * 4]) = l4;
        }
    }
    __syncthreads();

    f32x4 acc[4][2];
    #pragma unroll
    for (int i = 0; i < 4; i++)
        #pragma unroll
        for (int j = 0; j < 2; j++) acc[i][j] = (f32x4){0.f, 0.f, 0.f, 0.f};

    const ushort* WhB = Wh + (size_t)(wave * 32 + lane16) * 256 + quad * 8;
    const ushort* WlB = Wl + (size_t)(wave * 32 + lane16) * 256 + quad * 8;

    // --- K-loop: barrier-free, split A and split B (3 MFMA) ---------------
    #pragma unroll
    for (int kt = 0; kt < 8; kt++) {
        const int k0 = kt * 32;
        short8 ah[4], alo[4];
        #pragma unroll
        for (int mf = 0; mf < 4; mf++) {
            int m = mf * 16 + lane16;
            ah[mf]  = *(const short8*)(&Ah[m * SAK + k0 + quad * 8]);
            alo[mf] = *(const short8*)(&Al[m * SAK + k0 + quad * 8]);
        }
        #pragma unroll
        for (int nf = 0; nf < 2; nf++) {
            short8 bh = *(const short8*)(WhB + (size_t)nf * 4096 + k0);
            short8 bl = *(const short8*)(WlB + (size_t)nf * 4096 + k0);
            #pragma unroll
            for (int mf = 0; mf < 4; mf++) {
                acc[mf][nf] = __builtin_amdgcn_mfma_f32_16x16x32_bf16(ah[mf],  bh, acc[mf][nf], 0, 0, 0);
                acc[mf][nf] = __builtin_amdgcn_mfma_f32_16x16x32_bf16(ah[mf],  bl, acc[mf][nf], 0, 0, 0);
                acc[mf][nf] = __builtin_amdgcn_mfma_f32_16x16x32_bf16(alo[mf], bh, acc[mf][nf], 0, 0, 0);
            }
        }
    }

    // --- dump acc into LDS tile -------------------------------------------
    __syncthreads();
    #pragma unroll
    for (int mf = 0; mf < 4; mf++)
        #pragma unroll
        for (int nf = 0; nf < 2; nf++) {
            int row = mf * 16 + quad * 4;
            int col = wave * 32 + nf * 16 + lane16;
            #pragma unroll
            for (int r = 0; r < 4; r++)
                Tile[(row + r) * STL + col] = acc[mf][nf][r];
        }
    __syncthreads();

    // --- hierarchical parallel scan: wave w owns rows 8w..8w+7 ------------
    const float4 Alb = *(const float4*)(ws + WS_LB + 4 * lane);
    float4 v[8];
    {
        const float* Trow = Tile + (wave * 8) * STL + 4 * lane;
        float4 x = make_float4(0.f, 0.f, 0.f, 0.f);
        #pragma unroll
        for (int r = 0; r < 8; r++) {
            x = cfma2(Alb, x, *(const float4*)(Trow + r * STL));
            v[r] = x;
        }
    }
    __syncthreads();
    *(float4*)(Tile + wave * STL + 4 * lane) = v[7];   // 8 segment sums
    __syncthreads();
    if (wave == 0) {
        const float4 A8 = *(const float4*)(ws + WS_APOW + 7 * P2 + 4 * lane); // Lb^8
        float4 c = make_float4(0.f, 0.f, 0.f, 0.f);
        #pragma unroll
        for (int j = 0; j < 8; j++) {
            const float4 s = *(const float4*)(Tile + j * STL + 4 * lane);
            *(float4*)(Tile + (8 + j) * STL + 4 * lane) = c;
            c = cfma2(A8, c, s);
        }
    }
    __syncthreads();
    const float4 cs = *(const float4*)(Tile + (8 + wave) * STL + 4 * lane);
    // xs_local[8w+r] = v_r + Lb^{r+1} * cs ; store bf16
    ushort* g16 = xs16 + (size_t)(l0 + wave * 8) * 256 + 4 * lane;
    #pragma unroll
    for (int r = 0; r < 8; r++) {
        const float4 ap = *(const float4*)(ws + WS_APOW + (size_t)r * P2 + 4 * lane);
        const float4 y = cfma2(ap, cs, v[r]);
        ushort4 q;
        q.x = rne_bf16(y.x);  q.y = rne_bf16(y.y);
        q.z = rne_bf16(y.z);  q.w = rne_bf16(y.w);
        *(ushort4*)(g16 + (size_t)r * 256) = q;
        if (r == 7 && wave == 7)
            *(float4*)(E + (size_t)blk * P2 + 4 * lane) = y;   // chunk summary f32
    }
}

// ---------------------------------------------------------------------------
// GEMM2: out = (xs + Apow*carry) @ W2 + D*u.  Carry computed in-prologue from
// E via mod-8 wave-split ascending fold (R5-verified algebra). A is bf16-hi
// only -> 1 MFMA per fragment; direct scattered epilogue (R0-proven).
// LDS = Ah only (33792 B).
__global__ __launch_bounds__(TPB, 4) void k_gemm2(
        const ushort* __restrict__ xs16, const ushort* __restrict__ w2h,
        float* __restrict__ out, const float* __restrict__ Dv,
        const float* __restrict__ u, const float* __restrict__ ws,
        const float* __restrict__ E) {
    __shared__ ushort Ah[ROWS * SAK];            // 33792 B
    float* Csh = (float*)Ah;                     // alias: carry scratch (8 KB)

    const int t      = threadIdx.x;
    const int lane   = t & 63;
    const int wave   = t >> 6;        // 0..7
    const int lane16 = lane & 15;
    const int quad   = lane >> 4;
    const int blk    = blockIdx.x;
    const int l0     = blk * ROWS;

    // --- issue xs loads early (hide HBM latency under carry fold) ---------
    ushort4 xr[8];
    #pragma unroll
    for (int j = 0; j < 8; j++)
        xr[j] = *(const ushort4*)(xs16 + (size_t)(l0 + j*8 + wave) * 256 + 4 * lane);

    // --- carry fold: c = sum_{j<blk} Lb^{64(blk-1-j)} E[j], wave-split mod 8
    // ascending (oldest first): p = A512*p + E[j]; align by Lb^{64 d}.
    float4 c = make_float4(0.f, 0.f, 0.f, 0.f);
    {
        float4 p = make_float4(0.f, 0.f, 0.f, 0.f);
        const int cnt = (blk > wave) ? (((blk - 1 - wave) >> 3) + 1) : 0;
        if (cnt > 0) {
            const float4 A5 = *(const float4*)(ws + WS_A512 + 4 * lane);
            const float* ep = E + (size_t)wave * P2 + 4 * lane;
            for (int m = 0; m < cnt; m++) {
                p = cfma2(A5, p, *(const float4*)ep);
                ep += 8 * P2;
            }
            const int jmax = wave + ((cnt - 1) << 3);
            const int d = blk - 1 - jmax;              // 0..7
            const float4 Ad = *(const float4*)(ws + WS_A64P + (size_t)d * P2 + 4 * lane);
            const float4 z = make_float4(0.f, 0.f, 0.f, 0.f);
            p = cfma2(Ad, p, z);
        }
        *(float4*)(Csh + wave * P2 + 4 * lane) = p;
        __syncthreads();
        #pragma unroll
        for (int w2 = 0; w2 < NW; w2++) {
            const float4 q = *(const float4*)(Csh + w2 * P2 + 4 * lane);
            c.x += q.x; c.y += q.y; c.z += q.z; c.w += q.w;
        }
        __syncthreads();   // Csh reads done before Ah overwrite (alias)
    }

    // --- staging: f = cvt(xs) + Apow[row]*c, round to bf16 hi -> Ah -------
    #pragma unroll
    for (int j = 0; j < 8; j++) {
        const int m = j*8 + wave;
        float4 f;
        f.x = bf16_to_f32(xr[j].x);  f.y = bf16_to_f32(xr[j].y);
        f.z = bf16_to_f32(xr[j].z);  f.w = bf16_to_f32(xr[j].w);
        const float4 ap = *(const float4*)(ws + WS_APOW + (size_t)m * P2 + 4 * lane);
        f = cfma2(ap, c, f);
        ushort4 h4;
        h4.x = rne_bf16(f.x);  h4.y = rne_bf16(f.y);
        h4.z = rne_bf16(f.z);  h4.w = rne_bf16(f.w);
        *(ushort4*)(&Ah[m * SAK + lane * 4]) = h4;
    }
    __syncthreads();

    f32x4 acc[4][2];
    #pragma unroll
    for (int i = 0; i < 4; i++)
        #pragma unroll
        for (int j = 0; j < 2; j++) acc[i][j] = (f32x4){0.f, 0.f, 0.f, 0.f};

    const ushort* WB = w2h + (size_t)(wave * 32 + lane16) * 256 + quad * 8;

    // --- K-loop: 1 MFMA per fragment (A hi-only, B hi-only) ---------------
    #pragma unroll
    for (int kt = 0; kt < 8; kt++) {
        const int k0 = kt * 32;
        short8 ah[4];
        #pragma unroll
        for (int mf = 0; mf < 4; mf++)
            ah[mf] = *(const short8*)(&Ah[(mf * 16 + lane16) * SAK + k0 + quad * 8]);
        #pragma unroll
        for (int nf = 0; nf < 2; nf++) {
            short8 bh = *(const short8*)(WB + (size_t)nf * 4096 + k0);
            #pragma unroll
            for (int mf = 0; mf < 4; mf++)
                acc[mf][nf] = __builtin_amdgcn_mfma_f32_16x16x32_bf16(ah[mf], bh, acc[mf][nf], 0, 0, 0);
        }
    }

    // --- direct epilogue: out = acc + D*u (scattered 4 B, full 64 B lines)
    #pragma unroll
    for (int nf = 0; nf < 2; nf++) {
        const int col = wave * 32 + nf * 16 + lane16;
        const float dcol = Dv[col];
        #pragma unroll
        for (int mf = 0; mf < 4; mf++) {
            const int row0 = l0 + mf * 16 + quad * 4;
            #pragma unroll
            for (int r = 0; r < 4; r++) {
                const float uv = u[(size_t)(row0 + r) * 256 + col];
                out[(size_t)(row0 + r) * 256 + col] = acc[mf][nf][r] + dcol * uv;
            }
        }
    }
}

// ---------------------------------------------------------------------------
extern "C" void kernel_launch(void* const* d_in, const int* in_sizes, int n_in,
                              void* d_out, int out_size, void* d_ws, size_t ws_size,
                              hipStream_t stream) {
    const float* lre   = (const float*)d_in[0];  // Lambda_re (P)
    const float* lim   = (const float*)d_in[1];  // Lambda_im (P)
    const float* B     = (const float*)d_in[2];  // (P,H,2)
    const float* C     = (const float*)d_in[3];  // (H,P,2)
    const float* D     = (const float*)d_in[4];  // (H)
    const float* lstep = (const float*)d_in[5];  // (P)
    const float* u     = (const float*)d_in[6];  // (L,H)
    float* out = (float*)d_out;                  // (L,H) final output only
    float* ws  = (float*)d_ws;
    ushort* wpk  = (ushort*)(ws + WS_PACKS);
    ushort* w1h  = wpk;
    ushort* w1l  = wpk + 65536;
    ushort* w2h  = wpk + 131072;
    ushort* xs16 = (ushort*)(ws + WS_XS16);
    float*  E    = ws + WS_E;

    k_setup_p<<<1, 128, 0, stream>>>(lre, lim, lstep, ws);
    k_setup_mats<<<64, 256, 0, stream>>>(B, C, ws + WS_COEF, w1h, w1l, w2h);
    // GEMM1: xs_local (bf16) + chunk summaries E (f32)
    k_gemm1<<<NBLK, TPB, 0, stream>>>(u, w1h, w1l, xs16, ws, E);
    // GEMM2: in-prologue carry from E, apply, @W2, + D*u
    k_gemm2<<<NBLK, TPB, 0, stream>>>(xs16, w2h, out, D, u, ws, E);
}

// Round 8
// 136.734 us; speedup vs baseline: 1.8849x; 1.0791x over previous
//
#include <hip/hip_runtime.h>
#include <math.h>

// Problem constants
#define L_SEQ   32768
#define H_DIM   256
#define P_DIM   128
#define P2      256      // 2*P interleaved (re,im)
#define NBLK    512      // blocks: 64 rows each = exactly 1 chunk
#define ROWS    64       // rows per block (= chunk length)
#define TPB     512      // 8 waves per block
#define NW      8        // waves

// workspace layout (float offsets)
#define WS_LB    0                      // Lambda_bar                  256
#define WS_A64P  256                    // [8][P2] Lb^{64d}, d=0..7    2048
#define WS_A512  2304                   // Lb^512                      256
#define WS_COEF  2560                   // (Lb-1)/Lambda               256
#define WS_APOW  2816                   // [64][P2] Lb^{i+1}           16384
#define WS_E     19200                  // [512][P2] chunk summaries   131072
#define WS_PACKS 150272                 // ushort packs (3x32768 f)    98304
#define WS_XS16  248576                 // [L][P2] xs bf16 (ushort)    4194304 f

typedef __attribute__((ext_vector_type(8))) short short8;
typedef __attribute__((ext_vector_type(4))) float f32x4;

#define SAK 264   // LDS k-stride (ushorts) for A tile: 256 + 8 pad (2-way only)
#define STL 260   // LDS float stride for scan tile

// ---------------------------------------------------------------------------
// Fragment-major weight index: weights consumed only as MFMA B-fragments.
// For (n,k) in the [256][256] logical matrix: fragment f = wave*16+nf*8+kt
// (wave=n>>5, nf=(n>>4)&1, kt=k>>5) is 512 contiguous ushorts, lane-major
// (lane = quad*16+lane16, elem = k&7) -> each wave-load is 1 KB contiguous.
__device__ __forceinline__ size_t frag_idx(int n, int k) {
    return (size_t)(((n >> 5) * 16 + ((n >> 4) & 1) * 8 + (k >> 5)) * 512
                    + (((k >> 3) & 3) * 16 + (n & 15)) * 8 + (k & 7));
}

// ---------------------------------------------------------------------------
// Full-precision split (RNE both halves) — used for weights.
__device__ __forceinline__ void split_bf16(float v, ushort& hi, ushort& lo) {
    union { float f; unsigned u; } a; a.f = v;
    unsigned r = a.u + 0x7FFFu + ((a.u >> 16) & 1u);   // RNE to bf16
    hi = (ushort)(r >> 16);
    union { unsigned u; float f; } hf; hf.u = ((unsigned)hi) << 16;
    float rem = v - hf.f;
    union { float f; unsigned u; } b; b.f = rem;
    unsigned r2 = b.u + 0x7FFFu + ((b.u >> 16) & 1u);
    lo = (ushort)(r2 >> 16);
}

// Fast split for A-tile staging: trunc hi (lo compensates exactly), RNE lo.
__device__ __forceinline__ void split_bf16_fast(float v, ushort& hi, ushort& lo) {
    union { float f; unsigned u; } a; a.f = v;
    hi = (ushort)(a.u >> 16);                          // trunc toward zero
    union { unsigned u; float f; } hf; hf.u = a.u & 0xFFFF0000u;
    float rem = v - hf.f;                              // exact
    union { float f; unsigned u; } b; b.f = rem;
    unsigned r2 = b.u + 0x7FFFu + ((b.u >> 16) & 1u);  // RNE lo
    lo = (ushort)(r2 >> 16);
}

__device__ __forceinline__ ushort rne_bf16(float v) {
    union { float f; unsigned u; } a; a.f = v;
    return (ushort)((a.u + 0x7FFFu + ((a.u >> 16) & 1u)) >> 16);
}

__device__ __forceinline__ float bf16_to_f32(ushort h) {
    union { unsigned u; float f; } b; b.u = ((unsigned)h) << 16;
    return b.f;
}

// two packed complex: returns A*x + f  (layout r0,i0,r1,i1)
__device__ __forceinline__ float4 cfma2(const float4 A, const float4 x, const float4 f) {
    float4 o;
    o.x = A.x * x.x - A.y * x.y + f.x;
    o.y = A.x * x.y + A.y * x.x + f.y;
    o.z = A.z * x.z - A.w * x.w + f.z;
    o.w = A.z * x.w + A.w * x.z + f.w;
    return o;
}

// ---------------------------------------------------------------------------
// Setup 1: per-p quantities. 1 block, 128 threads.
__global__ void k_setup_p(const float* __restrict__ lre, const float* __restrict__ lim,
                          const float* __restrict__ lstep, float* __restrict__ ws) {
    int p = threadIdx.x;
    if (p >= P_DIM) return;
    float step = expf(lstep[p]);
    float lr = lre[p], li = lim[p];
    double zd = (double)lr * (double)step;
    double yd = (double)li * (double)step;
    double ed = exp(zd), cd = cos(yd), sd = sin(yd);
    double lbr = ed * cd, lbi = ed * sd;           // Lambda_bar (double)
    ws[WS_LB + 2*p]     = (float)lbr;
    ws[WS_LB + 2*p + 1] = (float)lbi;
    // Apow[i] = Lb^{i+1}, incremental, i = 0..63  (Apow[63] = Lb^64)
    double mr = lbr, mi = lbi;
    ws[WS_APOW + 2*p]     = (float)mr;
    ws[WS_APOW + 2*p + 1] = (float)mi;
    for (int i = 1; i < 64; i++) {
        double nr = mr * lbr - mi * lbi;
        mi = mr * lbi + mi * lbr;
        mr = nr;
        ws[WS_APOW + i*P2 + 2*p]     = (float)mr;
        ws[WS_APOW + i*P2 + 2*p + 1] = (float)mi;
    }
    // (mr,mi) == Lb^64.  A64P[d] = Lb^{64d}, d = 0..7
    double ar = 1.0, ai = 0.0;
    ws[WS_A64P + 2*p]     = 1.0f;
    ws[WS_A64P + 2*p + 1] = 0.0f;
    for (int d = 1; d < 8; d++) {
        double nr = ar * mr - ai * mi;
        ai = ar * mi + ai * mr;
        ar = nr;
        ws[WS_A64P + d*P2 + 2*p]     = (float)ar;
        ws[WS_A64P + d*P2 + 2*p + 1] = (float)ai;
    }
    // A512 = Lb^512 = A64P[7] * Lb^64
    double tr = ar * mr - ai * mi;
    double ti = ar * mi + ai * mr;
    ws[WS_A512 + 2*p]     = (float)tr;
    ws[WS_A512 + 2*p + 1] = (float)ti;
    // coef = (Lb - 1) / Lambda
    float lbrf = (float)lbr, lbif = (float)lbi;
    float a = lbrf - 1.0f, b = lbif;
    float den = lr*lr + li*li;
    ws[WS_COEF + 2*p]     = (a*lr + b*li) / den;
    ws[WS_COEF + 2*p + 1] = (b*lr - a*li) / den;
}

// ---------------------------------------------------------------------------
// Setup 2: build split-bf16 packed weights in FRAGMENT-MAJOR layout.
__global__ void k_setup_mats(const float* __restrict__ B, const float* __restrict__ C,
                             const float* __restrict__ coef,
                             ushort* __restrict__ w1h, ushort* __restrict__ w1l,
                             ushort* __restrict__ w2h) {
    int t = blockIdx.x * blockDim.x + threadIdx.x;   // 0..16383
    for (int e = t; e < P_DIM * H_DIM; e += 64 * 256) {
        int p = e >> 8;          // 0..127
        int h = e & 255;         // 0..255
        float br = B[(size_t)(p*H_DIM + h)*2 + 0];
        float bi = B[(size_t)(p*H_DIM + h)*2 + 1];
        float cr = coef[2*p], ci = coef[2*p + 1];
        float v1r = cr*br - ci*bi;
        float v1i = cr*bi + ci*br;
        ushort hi, lo;
        // W1: n = 2p (re) / 2p+1 (im), k = h
        split_bf16(v1r, hi, lo);
        w1h[frag_idx(2*p, h)] = hi;     w1l[frag_idx(2*p, h)] = lo;
        split_bf16(v1i, hi, lo);
        w1h[frag_idx(2*p+1, h)] = hi;   w1l[frag_idx(2*p+1, h)] = lo;
        // W2: n = h, k = 2p (re) / 2p+1 (im)
        float Cr = C[(size_t)(h*P_DIM + p)*2 + 0];
        float Ci = C[(size_t)(h*P_DIM + p)*2 + 1];
        split_bf16(2.0f*Cr, hi, lo);
        w2h[frag_idx(h, 2*p)] = hi;
        split_bf16(-2.0f*Ci, hi, lo);
        w2h[frag_idx(h, 2*p+1)] = hi;
    }
}

// ---------------------------------------------------------------------------
// GEMM1: xs_local = scan_local(u @ W1), split-bf16 MFMA (R3-proven config).
// 512 blocks x 512 thr (8 waves); wave owns 32-col slice; 4 mf x 2 nf.
// Weight loads: fragment-major, 1 KB contiguous per wave-load.
__global__ __launch_bounds__(TPB, 4) void k_gemm1(
        const float* __restrict__ u, const ushort* __restrict__ Wh,
        const ushort* __restrict__ Wl, ushort* __restrict__ xs16,
        const float* __restrict__ ws, float* __restrict__ E) {
    __shared__ float4 SMraw[4224];               // 67584 B
    ushort* Ah   = (ushort*)SMraw;               // [64][SAK]
    ushort* Al   = Ah + ROWS * SAK;
    float*  Tile = (float*)SMraw;                // [64][STL] alias (66560 B)

    const int t      = threadIdx.x;
    const int lane   = t & 63;
    const int wave   = t >> 6;        // 0..7
    const int lane16 = lane & 15;
    const int quad   = lane >> 4;
    const int blk    = blockIdx.x;
    const int l0     = blk * ROWS;

    // --- stage u tile (64 x 256) into LDS, split bf16 ---------------------
    {
        float4 f[8];
        #pragma unroll
        for (int j = 0; j < 8; j++)
            f[j] = *(const float4*)(u + (size_t)(l0 + j*8 + wave) * 256 + lane * 4);
        #pragma unroll
        for (int j = 0; j < 8; j++) {
            const int m = j*8 + wave;
            ushort4 h4, l4;
            split_bf16_fast(f[j].x, h4.x, l4.x);
            split_bf16_fast(f[j].y, h4.y, l4.y);
            split_bf16_fast(f[j].z, h4.z, l4.z);
            split_bf16_fast(f[j].w, h4.w, l4.w);
            *(ushort4*)(&Ah[m * SAK + lane * 4]) = h4;
            *(ushort4*)(&Al[m * SAK + lane * 4]) = l4;
        }
    }
    __syncthreads();

    f32x4 acc[4][2];
    #pragma unroll
    for (int i = 0; i < 4; i++)
        #pragma unroll
        for (int j = 0; j < 2; j++) acc[i][j] = (f32x4){0.f, 0.f, 0.f, 0.f};

    // fragment-major weight bases: frag (wave*16 + nf*8 + kt) * 512 + lane*8
    const ushort* WhB = Wh + (size_t)(wave * 16) * 512 + lane * 8;
    const ushort* WlB = Wl + (size_t)(wave * 16) * 512 + lane * 8;

    // --- K-loop: barrier-free, split A and split B (3 MFMA) ---------------
    #pragma unroll
    for (int kt = 0; kt < 8; kt++) {
        const int k0 = kt * 32;
        short8 ah[4], alo[4];
        #pragma unroll
        for (int mf = 0; mf < 4; mf++) {
            int m = mf * 16 + lane16;
            ah[mf]  = *(const short8*)(&Ah[m * SAK + k0 + quad * 8]);
            alo[mf] = *(const short8*)(&Al[m * SAK + k0 + quad * 8]);
        }
        #pragma unroll
        for (int nf = 0; nf < 2; nf++) {
            const size_t fo = (size_t)(nf * 8 + kt) * 512;
            short8 bh = *(const short8*)(WhB + fo);
            short8 bl = *(const short8*)(WlB + fo);
            #pragma unroll
            for (int mf = 0; mf < 4; mf++) {
                acc[mf][nf] = __builtin_amdgcn_mfma_f32_16x16x32_bf16(ah[mf],  bh, acc[mf][nf], 0, 0, 0);
                acc[mf][nf] = __builtin_amdgcn_mfma_f32_16x16x32_bf16(ah[mf],  bl, acc[mf][nf], 0, 0, 0);
                acc[mf][nf] = __builtin_amdgcn_mfma_f32_16x16x32_bf16(alo[mf], bh, acc[mf][nf], 0, 0, 0);
            }
        }
    }

    // --- dump acc into LDS tile -------------------------------------------
    __syncthreads();
    #pragma unroll
    for (int mf = 0; mf < 4; mf++)
        #pragma unroll
        for (int nf = 0; nf < 2; nf++) {
            int row = mf * 16 + quad * 4;
            int col = wave * 32 + nf * 16 + lane16;
            #pragma unroll
            for (int r = 0; r < 4; r++)
                Tile[(row + r) * STL + col] = acc[mf][nf][r];
        }
    __syncthreads();

    // --- hierarchical parallel scan: wave w owns rows 8w..8w+7 ------------
    const float4 Alb = *(const float4*)(ws + WS_LB + 4 * lane);
    float4 v[8];
    {
        const float* Trow = Tile + (wave * 8) * STL + 4 * lane;
        float4 x = make_float4(0.f, 0.f, 0.f, 0.f);
        #pragma unroll
        for (int r = 0; r < 8; r++) {
            x = cfma2(Alb, x, *(const float4*)(Trow + r * STL));
            v[r] = x;
        }
    }
    __syncthreads();
    *(float4*)(Tile + wave * STL + 4 * lane) = v[7];   // 8 segment sums
    __syncthreads();
    if (wave == 0) {
        const float4 A8 = *(const float4*)(ws + WS_APOW + 7 * P2 + 4 * lane); // Lb^8
        float4 c = make_float4(0.f, 0.f, 0.f, 0.f);
        #pragma unroll
        for (int j = 0; j < 8; j++) {
            const float4 s = *(const float4*)(Tile + j * STL + 4 * lane);
            *(float4*)(Tile + (8 + j) * STL + 4 * lane) = c;
            c = cfma2(A8, c, s);
        }
    }
    __syncthreads();
    const float4 cs = *(const float4*)(Tile + (8 + wave) * STL + 4 * lane);
    // xs_local[8w+r] = v_r + Lb^{r+1} * cs ; store bf16
    ushort* g16 = xs16 + (size_t)(l0 + wave * 8) * 256 + 4 * lane;
    #pragma unroll
    for (int r = 0; r < 8; r++) {
        const float4 ap = *(const float4*)(ws + WS_APOW + (size_t)r * P2 + 4 * lane);
        const float4 y = cfma2(ap, cs, v[r]);
        ushort4 q;
        q.x = rne_bf16(y.x);  q.y = rne_bf16(y.y);
        q.z = rne_bf16(y.z);  q.w = rne_bf16(y.w);
        *(ushort4*)(g16 + (size_t)r * 256) = q;
        if (r == 7 && wave == 7)
            *(float4*)(E + (size_t)blk * P2 + 4 * lane) = y;   // chunk summary f32
    }
}

// ---------------------------------------------------------------------------
// GEMM2: out = (xs + Apow*carry) @ W2 + D*u.  Carry computed in-prologue from
// E via mod-8 wave-split ascending fold (R5-verified algebra). A is bf16-hi
// only -> 1 MFMA per fragment; direct scattered epilogue (R0-proven).
// Weight loads fragment-major (1 KB contiguous). LDS = Ah only (33792 B).
__global__ __launch_bounds__(TPB, 4) void k_gemm2(
        const ushort* __restrict__ xs16, const ushort* __restrict__ w2h,
        float* __restrict__ out, const float* __restrict__ Dv,
        const float* __restrict__ u, const float* __restrict__ ws,
        const float* __restrict__ E) {
    __shared__ ushort Ah[ROWS * SAK];            // 33792 B
    float* Csh = (float*)Ah;                     // alias: carry scratch (8 KB)

    const int t      = threadIdx.x;
    const int lane   = t & 63;
    const int wave   = t >> 6;        // 0..7
    const int lane16 = lane & 15;
    const int quad   = lane >> 4;
    const int blk    = blockIdx.x;
    const int l0     = blk * ROWS;

    // --- issue xs loads early (hide HBM latency under carry fold) ---------
    ushort4 xr[8];
    #pragma unroll
    for (int j = 0; j < 8; j++)
        xr[j] = *(const ushort4*)(xs16 + (size_t)(l0 + j*8 + wave) * 256 + 4 * lane);

    // --- carry fold: c = sum_{j<blk} Lb^{64(blk-1-j)} E[j], wave-split mod 8
    // ascending (oldest first): p = A512*p + E[j]; align by Lb^{64 d}.
    float4 c = make_float4(0.f, 0.f, 0.f, 0.f);
    {
        float4 p = make_float4(0.f, 0.f, 0.f, 0.f);
        const int cnt = (blk > wave) ? (((blk - 1 - wave) >> 3) + 1) : 0;
        if (cnt > 0) {
            const float4 A5 = *(const float4*)(ws + WS_A512 + 4 * lane);
            const float* ep = E + (size_t)wave * P2 + 4 * lane;
            for (int m = 0; m < cnt; m++) {
                p = cfma2(A5, p, *(const float4*)ep);
                ep += 8 * P2;
            }
            const int jmax = wave + ((cnt - 1) << 3);
            const int d = blk - 1 - jmax;              // 0..7
            const float4 Ad = *(const float4*)(ws + WS_A64P + (size_t)d * P2 + 4 * lane);
            const float4 z = make_float4(0.f, 0.f, 0.f, 0.f);
            p = cfma2(Ad, p, z);
        }
        *(float4*)(Csh + wave * P2 + 4 * lane) = p;
        __syncthreads();
        #pragma unroll
        for (int w2 = 0; w2 < NW; w2++) {
            const float4 q = *(const float4*)(Csh + w2 * P2 + 4 * lane);
            c.x += q.x; c.y += q.y; c.z += q.z; c.w += q.w;
        }
        __syncthreads();   // Csh reads done before Ah overwrite (alias)
    }

    // --- staging: f = cvt(xs) + Apow[row]*c, round to bf16 hi -> Ah -------
    #pragma unroll
    for (int j = 0; j < 8; j++) {
        const int m = j*8 + wave;
        float4 f;
        f.x = bf16_to_f32(xr[j].x);  f.y = bf16_to_f32(xr[j].y);
        f.z = bf16_to_f32(xr[j].z);  f.w = bf16_to_f32(xr[j].w);
        const float4 ap = *(const float4*)(ws + WS_APOW + (size_t)m * P2 + 4 * lane);
        f = cfma2(ap, c, f);
        ushort4 h4;
        h4.x = rne_bf16(f.x);  h4.y = rne_bf16(f.y);
        h4.z = rne_bf16(f.z);  h4.w = rne_bf16(f.w);
        *(ushort4*)(&Ah[m * SAK + lane * 4]) = h4;
    }
    __syncthreads();

    f32x4 acc[4][2];
    #pragma unroll
    for (int i = 0; i < 4; i++)
        #pragma unroll
        for (int j = 0; j < 2; j++) acc[i][j] = (f32x4){0.f, 0.f, 0.f, 0.f};

    const ushort* WB = w2h + (size_t)(wave * 16) * 512 + lane * 8;

    // --- K-loop: 1 MFMA per fragment (A hi-only, B hi-only) ---------------
    #pragma unroll
    for (int kt = 0; kt < 8; kt++) {
        const int k0 = kt * 32;
        short8 ah[4];
        #pragma unroll
        for (int mf = 0; mf < 4; mf++)
            ah[mf] = *(const short8*)(&Ah[(mf * 16 + lane16) * SAK + k0 + quad * 8]);
        #pragma unroll
        for (int nf = 0; nf < 2; nf++) {
            short8 bh = *(const short8*)(WB + (size_t)(nf * 8 + kt) * 512);
            #pragma unroll
            for (int mf = 0; mf < 4; mf++)
                acc[mf][nf] = __builtin_amdgcn_mfma_f32_16x16x32_bf16(ah[mf], bh, acc[mf][nf], 0, 0, 0);
        }
    }

    // --- direct epilogue: out = acc + D*u (scattered 4 B, full 64 B lines)
    #pragma unroll
    for (int nf = 0; nf < 2; nf++) {
        const int col = wave * 32 + nf * 16 + lane16;
        const float dcol = Dv[col];
        #pragma unroll
        for (int mf = 0; mf < 4; mf++) {
            const int row0 = l0 + mf * 16 + quad * 4;
            #pragma unroll
            for (int r = 0; r < 4; r++) {
                const float uv = u[(size_t)(row0 + r) * 256 + col];
                out[(size_t)(row0 + r) * 256 + col] = acc[mf][nf][r] + dcol * uv;
            }
        }
    }
}

// ---------------------------------------------------------------------------
extern "C" void kernel_launch(void* const* d_in, const int* in_sizes, int n_in,
                              void* d_out, int out_size, void* d_ws, size_t ws_size,
                              hipStream_t stream) {
    const float* lre   = (const float*)d_in[0];  // Lambda_re (P)
    const float* lim   = (const float*)d_in[1];  // Lambda_im (P)
    const float* B     = (const float*)d_in[2];  // (P,H,2)
    const float* C     = (const float*)d_in[3];  // (H,P,2)
    const float* D     = (const float*)d_in[4];  // (H)
    const float* lstep = (const float*)d_in[5];  // (P)
    const float* u     = (const float*)d_in[6];  // (L,H)
    float* out = (float*)d_out;                  // (L,H) final output only
    float* ws  = (float*)d_ws;
    ushort* wpk  = (ushort*)(ws + WS_PACKS);
    ushort* w1h  = wpk;
    ushort* w1l  = wpk + 65536;
    ushort* w2h  = wpk + 131072;
    ushort* xs16 = (ushort*)(ws + WS_XS16);
    float*  E    = ws + WS_E;

    k_setup_p<<<1, 128, 0, stream>>>(lre, lim, lstep, ws);
    k_setup_mats<<<64, 256, 0, stream>>>(B, C, ws + WS_COEF, w1h, w1l, w2h);
    // GEMM1: xs_local (bf16) + chunk summaries E (f32)
    k_gemm1<<<NBLK, TPB, 0, stream>>>(u, w1h, w1l, xs16, ws, E);
    // GEMM2: in-prologue carry from E, apply, @W2, + D*u
    k_gemm2<<<NBLK, TPB, 0, stream>>>(xs16, w2h, out, D, u, ws, E);
}